// Round 7
// baseline (91.731 us; speedup 1.0000x reference)
//
#include <hip/hip_runtime.h>
#include <stdint.h>

#define B_ 2
#define L_ 2048
#define D_ 512
#define H_ 8
#define DH_ 64

using frag8 = __attribute__((ext_vector_type(8))) short;   // 8 bf16 in 4 VGPRs
using f32x4 = __attribute__((ext_vector_type(4))) float;   // MFMA accumulator
using u32x4 = __attribute__((ext_vector_type(4))) unsigned int;

#define QSC 0.18033688011112042f   /* 0.125 * log2(e): exp2-domain scale folded into Q */

__device__ __forceinline__ unsigned short f2bf(float f) {
    unsigned int u = __float_as_uint(f);
    u += 0x7fffu + ((u >> 16) & 1u);      // RNE
    return (unsigned short)(u >> 16);
}

__device__ __forceinline__ unsigned int cvtpk(float lo, float hi_) {
    unsigned int r;
    asm("v_cvt_pk_bf16_f32 %0, %1, %2" : "=v"(r) : "v"(lo), "v"(hi_));
    return r;
}

__device__ __forceinline__ void gl2lds16(const void* g, void* lds) {
    __builtin_amdgcn_global_load_lds((const __attribute__((address_space(1))) void*)g,
                                     (__attribute__((address_space(3))) void*)lds,
                                     16, 0, 0);
}

template<int N>
__device__ __forceinline__ void vmwait() {
    asm volatile("s_waitcnt vmcnt(%0)" :: "n"(N) : "memory");
}

// ---------------- prep: fp32 -> bf16 conversions + energy mask ----------------
__global__ __launch_bounds__(256) void cvt_mask_kernel(
    const float* __restrict__ qx, const float* __restrict__ kx, const float* __restrict__ vx,
    const float* __restrict__ Wq, const float* __restrict__ Wk, const float* __restrict__ Wv,
    const float* __restrict__ Wo, const float* __restrict__ ec,
    unsigned short* qb, unsigned short* kb, unsigned short* vb,
    unsigned short* wqb, unsigned short* wkb, unsigned short* wvb, unsigned short* wob,
    float* __restrict__ mk)
{
    const long NA = (long)B_ * L_ * D_;
    const long NW = (long)D_ * D_;
    const long total4 = (3 * NA + 4 * NW) / 4;
    long q4 = (long)blockIdx.x * 256 + threadIdx.x;
    if (q4 < total4) {
        long i = q4 * 4;
        const float* src; unsigned short* dst; long off;
        if (i < NA)            { src = qx; dst = qb; off = i; }
        else if (i < 2 * NA)   { src = kx; dst = kb; off = i - NA; }
        else if (i < 3 * NA)   { src = vx; dst = vb; off = i - 2 * NA; }
        else {
            long j = i - 3 * NA;
            int w = (int)(j / NW);
            off = j - (long)w * NW;
            src = (w == 0) ? Wq : (w == 1) ? Wk : (w == 2) ? Wv : Wo;
            dst = (w == 0) ? wqb : (w == 1) ? wkb : (w == 2) ? wvb : wob;
        }
        float4 v = *(const float4*)(src + off);
        ushort4 o;
        o.x = f2bf(v.x); o.y = f2bf(v.y); o.z = f2bf(v.z); o.w = f2bf(v.w);
        *(ushort4*)(dst + off) = o;
    } else {
        long i = q4 - total4;                     // 0..B*L-1 (tail blocks)
        if (i < B_ * L_) {
            const float4* p4 = (const float4*)(ec + i * 16);
            float s = 0.0f;
#pragma unroll
            for (int j = 0; j < 4; ++j) {
                float4 v = p4[j];
                s += fabsf(v.x) + fabsf(v.y) + fabsf(v.z) + fabsf(v.w);
            }
            float energy = s * (1.0f / 16.0f);
            mk[i] = (energy > 0.1f) ? 0.0f : -1.0e9f;
        }
    }
}

// ---------------- GEMM: C[M,N] = A[M,K] * W[N,K]^T + bias ----------------
// Double-buffered LDS, counted-vmcnt pipeline, raw barriers, XCD-chunked swizzle.
// mode 0: bf16 store; 1: bf16 * QSC (Q proj); 2: bf16 transposed V^T store with
// pi-slot permutation + XOR swizzle (PV b128 layout); 3: f32 store (out proj).
struct GemmArgs { const unsigned short* A; const unsigned short* W;
                  const float* bias; void* C; int mode; };

template<int BM, int BN>
__global__ __launch_bounds__(256) void gemm_kernel(GemmArgs a0, GemmArgs a1, GemmArgs a2,
                                                   int M, int N, int K)
{
    // XCD-chunked swizzle (grid size divisible by 8 by construction)
    const int nwg = gridDim.x * gridDim.y * gridDim.z;
    int flat = blockIdx.x + gridDim.x * (blockIdx.y + gridDim.y * blockIdx.z);
    int swz  = (flat & 7) * (nwg >> 3) + (flat >> 3);
    const int bx = swz % gridDim.x;
    int t2 = swz / gridDim.x;
    const int by = t2 % gridDim.y;
    const int bz = t2 / gridDim.y;

    GemmArgs ga = bz == 0 ? a0 : (bz == 1 ? a1 : a2);
    const unsigned short* __restrict__ A = ga.A;
    const unsigned short* __restrict__ W = ga.W;
    const float* __restrict__ bias = ga.bias;

    constexpr int MF = BM / 32;
    constexpr int NF = BN / 32;
    constexpr int NL = BM / 32 + BN / 32;

    __shared__ __align__(16) unsigned short As[2][BM * 64];
    __shared__ __align__(16) unsigned short Bs[2][BN * 64];

    const int tid  = threadIdx.x;
    const int lane = tid & 63;
    const int wave = tid >> 6;
    const int hi   = lane >> 4;
    const int ln   = lane & 15;
    const int wr   = wave >> 1;
    const int wc   = wave & 1;

    const long mBase = (long)by * BM;
    const long nBase = (long)bx * BN;

    f32x4 acc[MF][NF];
#pragma unroll
    for (int m = 0; m < MF; ++m)
#pragma unroll
        for (int n = 0; n < NF; ++n) acc[m][n] = (f32x4){0.f, 0.f, 0.f, 0.f};

#define GSTAGE(KT, BUF) do {                                                    \
    _Pragma("unroll")                                                           \
    for (int i_ = 0; i_ < BM / 32; ++i_) {                                      \
        int cl_ = i_ * 256 + tid;                                               \
        int r_ = cl_ >> 3, c_ = cl_ & 7, s_ = c_ ^ (r_ & 7);                    \
        gl2lds16(A + (mBase + r_) * K + (KT) + s_ * 8, As[BUF] + cl_ * 8);      \
    }                                                                           \
    _Pragma("unroll")                                                           \
    for (int i_ = 0; i_ < BN / 32; ++i_) {                                      \
        int cl_ = i_ * 256 + tid;                                               \
        int r_ = cl_ >> 3, c_ = cl_ & 7, s_ = c_ ^ (r_ & 7);                    \
        gl2lds16(W + (nBase + r_) * K + (KT) + s_ * 8, Bs[BUF] + cl_ * 8);      \
    }                                                                           \
} while (0)

    GSTAGE(0, 0);

    const int nk = K / 64;
    for (int t = 0; t < nk; ++t) {
        const int buf = t & 1;
        if (t + 1 < nk) {
            GSTAGE((t + 1) * 64, buf ^ 1);   // prefetch stays in flight across barriers
            vmwait<NL>();                     // wait only for tile t's loads
        } else {
            vmwait<0>();
        }
        __builtin_amdgcn_s_barrier();
        __builtin_amdgcn_sched_barrier(0);

        frag8 af[2][MF], bfr[2][NF];
#pragma unroll
        for (int kk = 0; kk < 2; ++kk) {
#pragma unroll
            for (int m = 0; m < MF; ++m) {
                int row = wr * (BM / 2) + m * 16 + ln;
                int c = (kk * 4 + hi) ^ (row & 7);
                af[kk][m] = *(const frag8*)(As[buf] + row * 64 + c * 8);
            }
#pragma unroll
            for (int n = 0; n < NF; ++n) {
                int row = wc * (BN / 2) + n * 16 + ln;
                int c = (kk * 4 + hi) ^ (row & 7);
                bfr[kk][n] = *(const frag8*)(Bs[buf] + row * 64 + c * 8);
            }
        }
        __builtin_amdgcn_s_setprio(1);
#pragma unroll
        for (int kk = 0; kk < 2; ++kk)
#pragma unroll
            for (int m = 0; m < MF; ++m)
#pragma unroll
                for (int n = 0; n < NF; ++n)
                    acc[m][n] = __builtin_amdgcn_mfma_f32_16x16x32_bf16(af[kk][m], bfr[kk][n], acc[m][n], 0, 0, 0);
        __builtin_amdgcn_s_setprio(0);
        __builtin_amdgcn_sched_barrier(0);
        __builtin_amdgcn_s_barrier();        // raw: prefetch stays in flight
    }
#undef GSTAGE

    const int mode = ga.mode;
#pragma unroll
    for (int m = 0; m < MF; ++m) {
#pragma unroll
        for (int n = 0; n < NF; ++n) {
            long col = nBase + wc * (BN / 2) + n * 16 + ln;
            float bv = bias[col];
#pragma unroll
            for (int j = 0; j < 4; ++j) {
                long row = mBase + wr * (BM / 2) + m * 16 + hi * 4 + j;
                float v = acc[m][n][j] + bv;
                if (mode == 3) {
                    ((float*)ga.C)[row * N + col] = v;
                } else if (mode == 2) {
                    // V^T store: pi-slot permutation + XOR((dh&7)<<1)
                    int dh = (int)col & 63;
                    int s  = ((int)row >> 2) & 15;
                    int w  = (int)row & 3;
                    int q  = ((((s & 3) << 2) | (s >> 2)) ^ ((dh & 7) << 1));
                    long nt = (row & ~63L) | (long)(q << 2) | w;
                    ((unsigned short*)ga.C)[col * (long)(B_ * L_) + nt] = f2bf(v);
                } else {
                    if (mode == 1) v *= QSC;
                    ((unsigned short*)ga.C)[row * N + col] = f2bf(v);
                }
            }
        }
    }
}

// ---------------- fused flash attention ----------------
// grid (L/64, B*H), 256 thr = 4 waves; each block owns 64 q-rows and iterates
// all 32 64-key tiles, double-buffered K/V in 32KB LDS (5 blocks/CU) with
// counted vmcnt. Q pre-scaled by 0.125*log2e -> exp2-domain softmax with
// defer-max (THR=8). V^T pre-permuted in global so PV = 2 contiguous b128
// LDS reads per d-block. No merge epilogue.
__global__ __launch_bounds__(256, 5) void attn_kernel(
    const unsigned short* __restrict__ Qg, const unsigned short* __restrict__ Kg,
    const unsigned short* __restrict__ Vt, const float* __restrict__ mkg,
    unsigned short* __restrict__ Og)
{
    const int tid  = threadIdx.x;
    const int lane = tid & 63;
    const int wave = tid >> 6;
    const int hi   = lane >> 4;
    const int ln   = lane & 15;

    const int bh = blockIdx.y;
    const int b  = bh >> 3, h = bh & 7;
    const unsigned short* Qb = Qg + ((long)b * L_) * D_ + h * DH_;
    const unsigned short* Kb = Kg + ((long)b * L_) * D_ + h * DH_;
    const unsigned short* Vb = Vt + (long)(h * DH_) * (B_ * L_) + (long)b * L_;
    const float* mkb = mkg + (long)b * L_;

    __shared__ __align__(16) unsigned short Ks[2][4096];
    __shared__ __align__(16) unsigned short Vs[2][4096];

    const int q0 = blockIdx.x * 64 + wave * 16;

    frag8 qf[2];
#pragma unroll
    for (int ks = 0; ks < 2; ++ks)
        qf[ks] = *(const frag8*)(Qb + (long)(q0 + ln) * D_ + ks * 32 + hi * 8);

    // PV read offsets (hoisted): position (4*hi [^2]) ^ ((ln&7)<<1), *4 ushorts
    const int xv   = (ln & 7) << 1;
    const int off0 = (((hi << 2) ^ xv)) << 2;
    const int off1 = off0 ^ 8;

#define STAGE(TT, BUF) do {                                                     \
    _Pragma("unroll")                                                           \
    for (int c2_ = 0; c2_ < 2; ++c2_) {                                         \
        int cl_ = c2_ * 256 + tid;                                              \
        int r_ = cl_ >> 3, c_ = cl_ & 7;                                        \
        gl2lds16(Kb + (long)((TT) * 64 + r_) * D_ + ((c_ ^ (r_ & 7)) << 3),     \
                 Ks[BUF] + cl_ * 8);                                            \
        gl2lds16(Vb + (long)r_ * (B_ * L_) + (TT) * 64 + (c_ << 3),             \
                 Vs[BUF] + cl_ * 8);                                            \
    }                                                                           \
} while (0)

    STAGE(0, 0);   // 4 loads; waited inside iteration 0

    f32x4 o[4];
#pragma unroll
    for (int g = 0; g < 4; ++g) o[g] = (f32x4){0.f, 0.f, 0.f, 0.f};
    float m_run = -__builtin_inff();
    float l_run = 0.0f;

#pragma unroll 2
    for (int i = 0; i < 32; ++i) {
        const int buf = i & 1;

        // mask loads FIRST (older than next STAGE)
        float4 m40 = *(const float4*)(mkb + i * 64 +      4 * hi);
        float4 m41 = *(const float4*)(mkb + i * 64 + 16 + 4 * hi);
        float4 m42 = *(const float4*)(mkb + i * 64 + 32 + 4 * hi);
        float4 m43 = *(const float4*)(mkb + i * 64 + 48 + 4 * hi);
        __builtin_amdgcn_sched_barrier(0);

        if (i < 31) {
            STAGE(i + 1, buf ^ 1);   // 4 loads, stay in flight
            vmwait<8>();             // tile i's 4 loads done
        } else {
            vmwait<4>();
        }
        __builtin_amdgcn_s_barrier();
        __builtin_amdgcn_sched_barrier(0);

        const unsigned short* Kl = Ks[buf];
        const unsigned short* Vl = Vs[buf];

        // ---- QK^T: S^T quarters, lane holds q=ln, keys sh*16+4*hi+r ----
        f32x4 sv[4];
#pragma unroll
        for (int sh = 0; sh < 4; ++sh) sv[sh] = (f32x4){0.f, 0.f, 0.f, 0.f};
        __builtin_amdgcn_s_setprio(1);
#pragma unroll
        for (int sh = 0; sh < 4; ++sh) {
            int key = sh * 16 + ln;
#pragma unroll
            for (int ks = 0; ks < 2; ++ks) {
                frag8 kf = *(const frag8*)(Kl + key * 64 + (((ks * 4 + hi) ^ (ln & 7)) << 3));
                sv[sh] = __builtin_amdgcn_mfma_f32_16x16x32_bf16(kf, qf[ks], sv[sh], 0, 0, 0);
            }
        }
        __builtin_amdgcn_s_setprio(0);

        // ---- mask add (scale already folded into Q) ----
        float sc[16];
        sc[0]  = sv[0][0] + m40.x; sc[1]  = sv[0][1] + m40.y;
        sc[2]  = sv[0][2] + m40.z; sc[3]  = sv[0][3] + m40.w;
        sc[4]  = sv[1][0] + m41.x; sc[5]  = sv[1][1] + m41.y;
        sc[6]  = sv[1][2] + m41.z; sc[7]  = sv[1][3] + m41.w;
        sc[8]  = sv[2][0] + m42.x; sc[9]  = sv[2][1] + m42.y;
        sc[10] = sv[2][2] + m42.z; sc[11] = sv[2][3] + m42.w;
        sc[12] = sv[3][0] + m43.x; sc[13] = sv[3][1] + m43.y;
        sc[14] = sv[3][2] + m43.z; sc[15] = sv[3][3] + m43.w;

        // ---- online softmax (per q = ln), exp2 domain, 3-way butterfly ----
        float t0 = fmaxf(fmaxf(sc[0], sc[1]), fmaxf(sc[2], sc[3]));
        float t1 = fmaxf(fmaxf(sc[4], sc[5]), fmaxf(sc[6], sc[7]));
        float t2 = fmaxf(fmaxf(sc[8], sc[9]), fmaxf(sc[10], sc[11]));
        float t3 = fmaxf(fmaxf(sc[12], sc[13]), fmaxf(sc[14], sc[15]));
        float tl = fmaxf(fmaxf(t0, t1), fmaxf(t2, t3));
        float tA = __shfl_xor(tl, 16);
        float tB = __shfl_xor(tl, 32);
        float tC = __shfl_xor(tl, 48);
        float tmax = fmaxf(fmaxf(tl, tA), fmaxf(tB, tC));

        // defer-max (T13): rescale only if max grew by > 8 (exp2 dom: p <= 256)
        if (!__all(tmax <= m_run + 8.0f)) {
            float m_new = fmaxf(m_run, tmax);
            float alpha = __builtin_amdgcn_exp2f(m_run - m_new);
            float a0 = __shfl(alpha, 4 * hi + 0);
            float a1 = __shfl(alpha, 4 * hi + 1);
            float a2 = __shfl(alpha, 4 * hi + 2);
            float a3 = __shfl(alpha, 4 * hi + 3);
#pragma unroll
            for (int g = 0; g < 4; ++g) {
                o[g][0] *= a0; o[g][1] *= a1; o[g][2] *= a2; o[g][3] *= a3;
            }
            l_run *= alpha;
            m_run = m_new;
        }

        float p[16];
#pragma unroll
        for (int j = 0; j < 16; ++j) p[j] = __builtin_amdgcn_exp2f(sc[j] - m_run);
        float s01 = (p[0] + p[1]) + (p[2] + p[3]);
        float s23 = (p[4] + p[5]) + (p[6] + p[7]);
        float s45 = (p[8] + p[9]) + (p[10] + p[11]);
        float s67 = (p[12] + p[13]) + (p[14] + p[15]);
        float ps = (s01 + s23) + (s45 + s67);
        float pA = __shfl_xor(ps, 16);
        float pB = __shfl_xor(ps, 32);
        float pC = __shfl_xor(ps, 48);
        l_run += (ps + pA) + (pB + pC);

        // ---- pack P via v_cvt_pk_bf16_f32 ----
        union PU { u32x4 u; frag8 f; } p0u, p1u;
        p0u.u = (u32x4){cvtpk(p[0], p[1]),  cvtpk(p[2], p[3]),
                        cvtpk(p[4], p[5]),  cvtpk(p[6], p[7])};
        p1u.u = (u32x4){cvtpk(p[8], p[9]),  cvtpk(p[10], p[11]),
                        cvtpk(p[12], p[13]), cvtpk(p[14], p[15])};

        // ---- PV: 2 contiguous b128 reads per d-block from pi-permuted V^T ----
        __builtin_amdgcn_s_setprio(1);
#pragma unroll
        for (int g = 0; g < 4; ++g) {
            int base = (g * 16 + ln) * 64;
            frag8 vf0 = *(const frag8*)(Vl + base + off0);
            frag8 vf1 = *(const frag8*)(Vl + base + off1);
            o[g] = __builtin_amdgcn_mfma_f32_16x16x32_bf16(p0u.f, vf0, o[g], 0, 0, 0);
            o[g] = __builtin_amdgcn_mfma_f32_16x16x32_bf16(p1u.f, vf1, o[g], 0, 0, 0);
        }
        __builtin_amdgcn_s_setprio(0);

        __builtin_amdgcn_sched_barrier(0);
        __builtin_amdgcn_s_barrier();   // raw: next tile's loads stay in flight
    }
#undef STAGE

    // ---- normalize + store ----
    float li = 1.0f / l_run;
    float i0 = __shfl(li, 4 * hi + 0);
    float i1 = __shfl(li, 4 * hi + 1);
    float i2 = __shfl(li, 4 * hi + 2);
    float i3 = __shfl(li, 4 * hi + 3);
#pragma unroll
    for (int g = 0; g < 4; ++g) {
        const float iv[4] = {i0, i1, i2, i3};
#pragma unroll
        for (int j = 0; j < 4; ++j) {
            long idx = ((long)b * L_ + q0 + 4 * hi + j) * D_ + h * DH_ + g * 16 + ln;
            Og[idx] = f2bf(o[g][j] * iv[j]);
        }
    }
}

// ---------------- launch ----------------
extern "C" void kernel_launch(void* const* d_in, const int* in_sizes, int n_in,
                              void* d_out, int out_size, void* d_ws, size_t ws_size,
                              hipStream_t stream)
{
    const float* qx = (const float*)d_in[0];
    const float* kx = (const float*)d_in[1];
    const float* vx = (const float*)d_in[2];
    const float* ec = (const float*)d_in[3];
    const float* Wq = (const float*)d_in[4];
    const float* bq = (const float*)d_in[5];
    const float* Wk = (const float*)d_in[6];
    const float* bk = (const float*)d_in[7];
    const float* Wv = (const float*)d_in[8];
    const float* bv = (const float*)d_in[9];
    const float* Wo = (const float*)d_in[10];
    const float* bo = (const float*)d_in[11];
    float* out = (float*)d_out;

    const long NA = (long)B_ * L_ * D_;
    const long NW = (long)D_ * D_;

    unsigned short* qb  = (unsigned short*)d_ws;
    unsigned short* kb  = qb + NA;
    unsigned short* vb  = kb + NA;
    unsigned short* wqb = vb + NA;
    unsigned short* wkb = wqb + NW;
    unsigned short* wvb = wkb + NW;
    unsigned short* wob = wvb + NW;
    unsigned short* Qp  = wob + NW;
    unsigned short* Kp  = Qp + NA;
    unsigned short* Vtp = Kp + NA;       // V^T: [D][B*L], pi-permuted+swizzled
    unsigned short* Ap  = qb;            // alias: qb dead after Q GEMM
    float*          mk  = (float*)(Vtp + NA);

    const long total4 = (3 * NA + 4 * NW) / 4;
    const long nblk = (total4 + B_ * L_ + 255) / 256;
    cvt_mask_kernel<<<dim3((unsigned)nblk), dim3(256), 0, stream>>>(
        qx, kx, vx, Wq, Wk, Wv, Wo, ec, qb, kb, vb, wqb, wkb, wvb, wob, mk);

    // fused QKV projections (768 blocks): Q scaled, K plain, V transposed+permuted
    GemmArgs zq = {qb, wqb, bq, Qp, 1};
    GemmArgs zk = {kb, wkb, bk, Kp, 0};
    GemmArgs zv = {vb, wvb, bv, Vtp, 2};
    gemm_kernel<64, 128><<<dim3(4, 64, 3), dim3(256), 0, stream>>>(zq, zk, zv, B_ * L_, D_, D_);

    attn_kernel<<<dim3(L_ / 64, B_ * H_), dim3(256), 0, stream>>>(Qp, Kp, Vtp, mk, Ap);

    // output projection, f32 out (512 blocks)
    GemmArgs zo = {Ap, wob, bo, out, 3};
    gemm_kernel<64, 64><<<dim3(8, 64, 1), dim3(256), 0, stream>>>(zo, zo, zo, B_ * L_, D_, D_);
}

// Round 8
// 75.338 us; speedup vs baseline: 1.2176x; 1.2176x over previous
//
#include <hip/hip_runtime.h>
#include <stdint.h>

#define B_ 2
#define L_ 2048
#define D_ 512
#define H_ 8
#define DH_ 64

using frag8 = __attribute__((ext_vector_type(8))) short;   // 8 bf16 in 4 VGPRs
using bf4   = __attribute__((ext_vector_type(4))) short;   // 4 bf16 (one b64)
using f32x4 = __attribute__((ext_vector_type(4))) float;   // MFMA accumulator
using u32x4 = __attribute__((ext_vector_type(4))) unsigned int;

#define QSC 0.18033688011112042f   /* 0.125 * log2(e): exp2-domain scale folded into Q */

__device__ __forceinline__ unsigned short f2bf(float f) {
    unsigned int u = __float_as_uint(f);
    u += 0x7fffu + ((u >> 16) & 1u);      // RNE
    return (unsigned short)(u >> 16);
}

__device__ __forceinline__ unsigned int cvtpk(float lo, float hi_) {
    unsigned int r;
    asm("v_cvt_pk_bf16_f32 %0, %1, %2" : "=v"(r) : "v"(lo), "v"(hi_));
    return r;
}

__device__ __forceinline__ void gl2lds16(const void* g, void* lds) {
    __builtin_amdgcn_global_load_lds((const __attribute__((address_space(1))) void*)g,
                                     (__attribute__((address_space(3))) void*)lds,
                                     16, 0, 0);
}

template<int N>
__device__ __forceinline__ void vmwait() {
    asm volatile("s_waitcnt vmcnt(%0)" :: "n"(N) : "memory");
}

// ---------------- prep: fp32 -> bf16 conversions + energy mask ----------------
__global__ __launch_bounds__(256) void cvt_mask_kernel(
    const float* __restrict__ qx, const float* __restrict__ kx, const float* __restrict__ vx,
    const float* __restrict__ Wq, const float* __restrict__ Wk, const float* __restrict__ Wv,
    const float* __restrict__ Wo, const float* __restrict__ ec,
    unsigned short* qb, unsigned short* kb, unsigned short* vb,
    unsigned short* wqb, unsigned short* wkb, unsigned short* wvb, unsigned short* wob,
    float* __restrict__ mk)
{
    const long NA = (long)B_ * L_ * D_;
    const long NW = (long)D_ * D_;
    const long total4 = (3 * NA + 4 * NW) / 4;
    long q4 = (long)blockIdx.x * 256 + threadIdx.x;
    if (q4 < total4) {
        long i = q4 * 4;
        const float* src; unsigned short* dst; long off;
        if (i < NA)            { src = qx; dst = qb; off = i; }
        else if (i < 2 * NA)   { src = kx; dst = kb; off = i - NA; }
        else if (i < 3 * NA)   { src = vx; dst = vb; off = i - 2 * NA; }
        else {
            long j = i - 3 * NA;
            int w = (int)(j / NW);
            off = j - (long)w * NW;
            src = (w == 0) ? Wq : (w == 1) ? Wk : (w == 2) ? Wv : Wo;
            dst = (w == 0) ? wqb : (w == 1) ? wkb : (w == 2) ? wvb : wob;
        }
        float4 v = *(const float4*)(src + off);
        ushort4 o;
        o.x = f2bf(v.x); o.y = f2bf(v.y); o.z = f2bf(v.z); o.w = f2bf(v.w);
        *(ushort4*)(dst + off) = o;
    } else {
        long i = q4 - total4;                     // 0..B*L-1 (tail blocks)
        if (i < B_ * L_) {
            const float4* p4 = (const float4*)(ec + i * 16);
            float s = 0.0f;
#pragma unroll
            for (int j = 0; j < 4; ++j) {
                float4 v = p4[j];
                s += fabsf(v.x) + fabsf(v.y) + fabsf(v.z) + fabsf(v.w);
            }
            float energy = s * (1.0f / 16.0f);
            mk[i] = (energy > 0.1f) ? 0.0f : -1.0e9f;
        }
    }
}

// ---------------- GEMM: C[M,N] = A[M,K] * W[N,K]^T + bias ----------------
// Double-buffered LDS, counted-vmcnt pipeline, raw barriers, XCD-chunked swizzle.
// mode 0: bf16 store; 1: bf16 * QSC (Q proj); 2: bf16 transposed V^T store with
// R5 slot swizzle (conflict-free b64 PV); 3: f32 store (out proj).
struct GemmArgs { const unsigned short* A; const unsigned short* W;
                  const float* bias; void* C; int mode; };

template<int BM, int BN>
__global__ __launch_bounds__(256) void gemm_kernel(GemmArgs a0, GemmArgs a1, GemmArgs a2,
                                                   int M, int N, int K)
{
    // XCD-chunked swizzle (grid size divisible by 8 by construction)
    const int nwg = gridDim.x * gridDim.y * gridDim.z;
    int flat = blockIdx.x + gridDim.x * (blockIdx.y + gridDim.y * blockIdx.z);
    int swz  = (flat & 7) * (nwg >> 3) + (flat >> 3);
    const int bx = swz % gridDim.x;
    int t2 = swz / gridDim.x;
    const int by = t2 % gridDim.y;
    const int bz = t2 / gridDim.y;

    GemmArgs ga = bz == 0 ? a0 : (bz == 1 ? a1 : a2);
    const unsigned short* __restrict__ A = ga.A;
    const unsigned short* __restrict__ W = ga.W;
    const float* __restrict__ bias = ga.bias;

    constexpr int MF = BM / 32;
    constexpr int NF = BN / 32;
    constexpr int NL = BM / 32 + BN / 32;

    __shared__ __align__(16) unsigned short As[2][BM * 64];
    __shared__ __align__(16) unsigned short Bs[2][BN * 64];

    const int tid  = threadIdx.x;
    const int lane = tid & 63;
    const int wave = tid >> 6;
    const int hi   = lane >> 4;
    const int ln   = lane & 15;
    const int wr   = wave >> 1;
    const int wc   = wave & 1;

    const long mBase = (long)by * BM;
    const long nBase = (long)bx * BN;

    f32x4 acc[MF][NF];
#pragma unroll
    for (int m = 0; m < MF; ++m)
#pragma unroll
        for (int n = 0; n < NF; ++n) acc[m][n] = (f32x4){0.f, 0.f, 0.f, 0.f};

#define GSTAGE(KT, BUF) do {                                                    \
    _Pragma("unroll")                                                           \
    for (int i_ = 0; i_ < BM / 32; ++i_) {                                      \
        int cl_ = i_ * 256 + tid;                                               \
        int r_ = cl_ >> 3, c_ = cl_ & 7, s_ = c_ ^ (r_ & 7);                    \
        gl2lds16(A + (mBase + r_) * K + (KT) + s_ * 8, As[BUF] + cl_ * 8);      \
    }                                                                           \
    _Pragma("unroll")                                                           \
    for (int i_ = 0; i_ < BN / 32; ++i_) {                                      \
        int cl_ = i_ * 256 + tid;                                               \
        int r_ = cl_ >> 3, c_ = cl_ & 7, s_ = c_ ^ (r_ & 7);                    \
        gl2lds16(W + (nBase + r_) * K + (KT) + s_ * 8, Bs[BUF] + cl_ * 8);      \
    }                                                                           \
} while (0)

    GSTAGE(0, 0);

    const int nk = K / 64;
    for (int t = 0; t < nk; ++t) {
        const int buf = t & 1;
        if (t + 1 < nk) {
            GSTAGE((t + 1) * 64, buf ^ 1);   // prefetch stays in flight across barriers
            vmwait<NL>();                     // wait only for tile t's loads
        } else {
            vmwait<0>();
        }
        __builtin_amdgcn_s_barrier();
        __builtin_amdgcn_sched_barrier(0);

        frag8 af[2][MF], bfr[2][NF];
#pragma unroll
        for (int kk = 0; kk < 2; ++kk) {
#pragma unroll
            for (int m = 0; m < MF; ++m) {
                int row = wr * (BM / 2) + m * 16 + ln;
                int c = (kk * 4 + hi) ^ (row & 7);
                af[kk][m] = *(const frag8*)(As[buf] + row * 64 + c * 8);
            }
#pragma unroll
            for (int n = 0; n < NF; ++n) {
                int row = wc * (BN / 2) + n * 16 + ln;
                int c = (kk * 4 + hi) ^ (row & 7);
                bfr[kk][n] = *(const frag8*)(Bs[buf] + row * 64 + c * 8);
            }
        }
        __builtin_amdgcn_s_setprio(1);
#pragma unroll
        for (int kk = 0; kk < 2; ++kk)
#pragma unroll
            for (int m = 0; m < MF; ++m)
#pragma unroll
                for (int n = 0; n < NF; ++n)
                    acc[m][n] = __builtin_amdgcn_mfma_f32_16x16x32_bf16(af[kk][m], bfr[kk][n], acc[m][n], 0, 0, 0);
        __builtin_amdgcn_s_setprio(0);
        __builtin_amdgcn_sched_barrier(0);
        __builtin_amdgcn_s_barrier();        // raw: prefetch stays in flight
    }
#undef GSTAGE

    const int mode = ga.mode;
#pragma unroll
    for (int m = 0; m < MF; ++m) {
#pragma unroll
        for (int n = 0; n < NF; ++n) {
            long col = nBase + wc * (BN / 2) + n * 16 + ln;
            float bv = bias[col];
#pragma unroll
            for (int j = 0; j < 4; ++j) {
                long row = mBase + wr * (BM / 2) + m * 16 + hi * 4 + j;
                float v = acc[m][n][j] + bv;
                if (mode == 3) {
                    ((float*)ga.C)[row * N + col] = v;
                } else if (mode == 2) {
                    // V^T store: R5 slot swizzle (key-group s at s^sw within 64)
                    int dh = (int)col & 63;
                    int swv = ((dh & 7) << 1) | ((dh >> 3) & 1);
                    long nt = (row & ~63L) | (long)(((((int)(row >> 2)) & 15) ^ swv) << 2) | (row & 3);
                    ((unsigned short*)ga.C)[col * (long)(B_ * L_) + nt] = f2bf(v);
                } else {
                    if (mode == 1) v *= QSC;
                    ((unsigned short*)ga.C)[row * N + col] = f2bf(v);
                }
            }
        }
    }
}

// ---------------- fused flash attention ----------------
// grid (L/64, B*H), 512 thr = 8 waves. Waves 0-3 (group 0) = even 64-key tiles,
// waves 4-7 (group 1) = odd tiles; each group double-buffers its own K/V in LDS.
// SINGLE barrier per iteration (dbuf invariant: barrier at iter start => all
// waves done with iter i-1 => buf[i^1] free; own vmcnt(0) + barrier => buf[i]
// valid). Q pre-scaled by 0.125*log2e -> exp2-domain softmax, defer-max THR=8.
// V^T slot-swizzled in global (R5 layout): conflict-free b64 PV reads.
__global__ __launch_bounds__(512, 4) void attn_kernel(
    const unsigned short* __restrict__ Qg, const unsigned short* __restrict__ Kg,
    const unsigned short* __restrict__ Vt, const float* __restrict__ mkg,
    unsigned short* __restrict__ Og)
{
    const int tid  = threadIdx.x;
    const int lane = tid & 63;
    const int wave = tid >> 6;
    const int grp  = wave >> 2;
    const int wq   = wave & 3;
    const int gtid = tid & 255;
    const int hi   = lane >> 4;
    const int ln   = lane & 15;

    const int bh = blockIdx.y;
    const int b  = bh >> 3, h = bh & 7;
    const unsigned short* Qb = Qg + ((long)b * L_) * D_ + h * DH_;
    const unsigned short* Kb = Kg + ((long)b * L_) * D_ + h * DH_;
    const unsigned short* Vb = Vt + (long)(h * DH_) * (B_ * L_) + (long)b * L_;
    const float* mkb = mkg + (long)b * L_;

    __shared__ __align__(16) char smem[65536];
    unsigned short* KsG = (unsigned short*)(smem + grp * 32768);
    unsigned short* VsG = (unsigned short*)(smem + grp * 32768 + 16384);

    const int q0 = blockIdx.x * 64 + wq * 16;

    frag8 qf[2];
#pragma unroll
    for (int ks = 0; ks < 2; ++ks)
        qf[ks] = *(const frag8*)(Qb + (long)(q0 + ln) * D_ + ks * 32 + hi * 8);

    // hoisted PV slot offsets (V^T global swizzle: group s stored at s^sw)
    const int sw  = ((ln & 7) << 1) | ((ln >> 3) & 1);
    const int sl0 = ((hi     ) ^ sw) << 2;
    const int sl1 = ((hi + 4 ) ^ sw) << 2;
    const int sl2 = ((hi + 8 ) ^ sw) << 2;
    const int sl3 = ((hi + 12) ^ sw) << 2;

#define STAGE(TT, BUF) do {                                                     \
    _Pragma("unroll")                                                           \
    for (int c2_ = 0; c2_ < 2; ++c2_) {                                         \
        int cl_ = c2_ * 256 + gtid;                                             \
        int r_ = cl_ >> 3, c_ = cl_ & 7;                                        \
        gl2lds16(Kb + (long)((TT) * 64 + r_) * D_ + ((c_ ^ (r_ & 7)) << 3),     \
                 KsG + (BUF) * 4096 + cl_ * 8);                                 \
        gl2lds16(Vb + (long)r_ * (B_ * L_) + (TT) * 64 + (c_ << 3),             \
                 VsG + (BUF) * 4096 + cl_ * 8);                                 \
    }                                                                           \
} while (0)

    STAGE(grp, 0);   // prologue: 4 loads for tile 0

    f32x4 o[4];
#pragma unroll
    for (int g = 0; g < 4; ++g) o[g] = (f32x4){0.f, 0.f, 0.f, 0.f};
    float m_run = -__builtin_inff();
    float l_run = 0.0f;

    for (int i = 0; i < 16; ++i) {
        const int T = 2 * i + grp;
        const int buf = i & 1;

        // single sync point per iteration: my STAGE(i) done + everyone past
        // iter i-1 (=> buf[i] valid for all, buf[i^1] free to overwrite)
        vmwait<0>();
        __builtin_amdgcn_s_barrier();
        __builtin_amdgcn_sched_barrier(0);

        // mask loads (used ~400cy later in softmax — latency hidden)
        float4 m40 = *(const float4*)(mkb + T * 64 +      4 * hi);
        float4 m41 = *(const float4*)(mkb + T * 64 + 16 + 4 * hi);
        float4 m42 = *(const float4*)(mkb + T * 64 + 32 + 4 * hi);
        float4 m43 = *(const float4*)(mkb + T * 64 + 48 + 4 * hi);

        const unsigned short* Kl = KsG + buf * 4096;
        const unsigned short* Vl = VsG + buf * 4096;

        // ---- QK^T: S^T quarters, lane holds q=ln, keys sh*16+4*hi+r ----
        f32x4 sv[4];
#pragma unroll
        for (int sh = 0; sh < 4; ++sh) sv[sh] = (f32x4){0.f, 0.f, 0.f, 0.f};
        __builtin_amdgcn_s_setprio(1);
#pragma unroll
        for (int sh = 0; sh < 4; ++sh) {
            int key = sh * 16 + ln;
#pragma unroll
            for (int ks = 0; ks < 2; ++ks) {
                frag8 kf = *(const frag8*)(Kl + key * 64 + (((ks * 4 + hi) ^ (ln & 7)) << 3));
                sv[sh] = __builtin_amdgcn_mfma_f32_16x16x32_bf16(kf, qf[ks], sv[sh], 0, 0, 0);
            }
        }
        __builtin_amdgcn_s_setprio(0);

        // prefetch next tile into the buffer freed at this iteration's barrier
        if (i < 15) STAGE(2 * (i + 1) + grp, buf ^ 1);

        // ---- mask add (scale already folded into Q) ----
        float sc[16];
        sc[0]  = sv[0][0] + m40.x; sc[1]  = sv[0][1] + m40.y;
        sc[2]  = sv[0][2] + m40.z; sc[3]  = sv[0][3] + m40.w;
        sc[4]  = sv[1][0] + m41.x; sc[5]  = sv[1][1] + m41.y;
        sc[6]  = sv[1][2] + m41.z; sc[7]  = sv[1][3] + m41.w;
        sc[8]  = sv[2][0] + m42.x; sc[9]  = sv[2][1] + m42.y;
        sc[10] = sv[2][2] + m42.z; sc[11] = sv[2][3] + m42.w;
        sc[12] = sv[3][0] + m43.x; sc[13] = sv[3][1] + m43.y;
        sc[14] = sv[3][2] + m43.z; sc[15] = sv[3][3] + m43.w;

        // ---- online softmax (per q = ln), exp2 domain ----
        float t0 = fmaxf(fmaxf(sc[0], sc[1]), fmaxf(sc[2], sc[3]));
        float t1 = fmaxf(fmaxf(sc[4], sc[5]), fmaxf(sc[6], sc[7]));
        float t2 = fmaxf(fmaxf(sc[8], sc[9]), fmaxf(sc[10], sc[11]));
        float t3 = fmaxf(fmaxf(sc[12], sc[13]), fmaxf(sc[14], sc[15]));
        float tl = fmaxf(fmaxf(t0, t1), fmaxf(t2, t3));
        float tmax = fmaxf(tl, __shfl_xor(tl, 16));
        tmax = fmaxf(tmax, __shfl_xor(tmax, 32));

        // defer-max (T13): rescale only if max grew by > 8 (exp2 dom: p <= 256)
        if (!__all(tmax <= m_run + 8.0f)) {
            float m_new = fmaxf(m_run, tmax);
            float alpha = __builtin_amdgcn_exp2f(m_run - m_new);
            float a0 = __shfl(alpha, 4 * hi + 0);
            float a1 = __shfl(alpha, 4 * hi + 1);
            float a2 = __shfl(alpha, 4 * hi + 2);
            float a3 = __shfl(alpha, 4 * hi + 3);
#pragma unroll
            for (int g = 0; g < 4; ++g) {
                o[g][0] *= a0; o[g][1] *= a1; o[g][2] *= a2; o[g][3] *= a3;
            }
            l_run *= alpha;
            m_run = m_new;
        }

        float p[16];
#pragma unroll
        for (int j = 0; j < 16; ++j) p[j] = __builtin_amdgcn_exp2f(sc[j] - m_run);
        float s01 = (p[0] + p[1]) + (p[2] + p[3]);
        float s23 = (p[4] + p[5]) + (p[6] + p[7]);
        float s45 = (p[8] + p[9]) + (p[10] + p[11]);
        float s67 = (p[12] + p[13]) + (p[14] + p[15]);
        float ps = (s01 + s23) + (s45 + s67);
        ps += __shfl_xor(ps, 16);
        ps += __shfl_xor(ps, 32);
        l_run += ps;

        // ---- pack P via v_cvt_pk_bf16_f32 ----
        union PU { u32x4 u; frag8 f; } p0u, p1u;
        p0u.u = (u32x4){cvtpk(p[0], p[1]),  cvtpk(p[2], p[3]),
                        cvtpk(p[4], p[5]),  cvtpk(p[6], p[7])};
        p1u.u = (u32x4){cvtpk(p[8], p[9]),  cvtpk(p[10], p[11]),
                        cvtpk(p[12], p[13]), cvtpk(p[14], p[15])};

        // ---- PV: conflict-free b64 reads from slot-swizzled V^T ----
        __builtin_amdgcn_s_setprio(1);
#pragma unroll
        for (int g = 0; g < 4; ++g) {
            int rowb = (g * 16 + ln) * 64;
            bf4 a0 = *(const bf4*)(Vl + rowb + sl0);
            bf4 a1 = *(const bf4*)(Vl + rowb + sl1);
            bf4 a2 = *(const bf4*)(Vl + rowb + sl2);
            bf4 a3 = *(const bf4*)(Vl + rowb + sl3);
            frag8 vf0 = __builtin_shufflevector(a0, a1, 0, 1, 2, 3, 4, 5, 6, 7);
            frag8 vf1 = __builtin_shufflevector(a2, a3, 0, 1, 2, 3, 4, 5, 6, 7);
            o[g] = __builtin_amdgcn_mfma_f32_16x16x32_bf16(p0u.f, vf0, o[g], 0, 0, 0);
            o[g] = __builtin_amdgcn_mfma_f32_16x16x32_bf16(p1u.f, vf1, o[g], 0, 0, 0);
        }
        __builtin_amdgcn_s_setprio(0);
        // no end-of-iteration barrier (single-sync dbuf)
    }
#undef STAGE

    // ---- merge group 1 partials into group 0, write out ----
    __syncthreads();   // loop has no trailing barrier; protect smem reuse
    float* oX = (float*)smem;                       // [64][68] padded f32
    float* mX = (float*)(smem + 64 * 68 * 4);       // [64]
    float* lX = mX + 64;

    if (grp == 1) {
#pragma unroll
        for (int g = 0; g < 4; ++g)
#pragma unroll
            for (int j = 0; j < 4; ++j)
                oX[(wq * 16 + 4 * hi + j) * 68 + g * 16 + ln] = o[g][j];
        if (hi == 0) { mX[wq * 16 + ln] = m_run; lX[wq * 16 + ln] = l_run; }
    }
    __syncthreads();
    if (grp == 0) {
#pragma unroll
        for (int j = 0; j < 4; ++j) {
            int q = 4 * hi + j;
            float mA = __shfl(m_run, q);
            float lA = __shfl(l_run, q);
            float mB = mX[wq * 16 + q];
            float lB = lX[wq * 16 + q];
            float mm = fmaxf(mA, mB);
            float aA = __builtin_amdgcn_exp2f(mA - mm);
            float aB = __builtin_amdgcn_exp2f(mB - mm);
            float inv = 1.0f / (lA * aA + lB * aB);
            aA *= inv; aB *= inv;
#pragma unroll
            for (int g = 0; g < 4; ++g) {
                float v = o[g][j] * aA + oX[(wq * 16 + q) * 68 + g * 16 + ln] * aB;
                long idx = ((long)b * L_ + q0 + q) * D_ + h * DH_ + g * 16 + ln;
                Og[idx] = f2bf(v);
            }
        }
    }
}

// ---------------- launch ----------------
extern "C" void kernel_launch(void* const* d_in, const int* in_sizes, int n_in,
                              void* d_out, int out_size, void* d_ws, size_t ws_size,
                              hipStream_t stream)
{
    const float* qx = (const float*)d_in[0];
    const float* kx = (const float*)d_in[1];
    const float* vx = (const float*)d_in[2];
    const float* ec = (const float*)d_in[3];
    const float* Wq = (const float*)d_in[4];
    const float* bq = (const float*)d_in[5];
    const float* Wk = (const float*)d_in[6];
    const float* bk = (const float*)d_in[7];
    const float* Wv = (const float*)d_in[8];
    const float* bv = (const float*)d_in[9];
    const float* Wo = (const float*)d_in[10];
    const float* bo = (const float*)d_in[11];
    float* out = (float*)d_out;

    const long NA = (long)B_ * L_ * D_;
    const long NW = (long)D_ * D_;

    unsigned short* qb  = (unsigned short*)d_ws;
    unsigned short* kb  = qb + NA;
    unsigned short* vb  = kb + NA;
    unsigned short* wqb = vb + NA;
    unsigned short* wkb = wqb + NW;
    unsigned short* wvb = wkb + NW;
    unsigned short* wob = wvb + NW;
    unsigned short* Qp  = wob + NW;
    unsigned short* Kp  = Qp + NA;
    unsigned short* Vtp = Kp + NA;       // V^T: [D][B*L], slot-swizzled
    unsigned short* Ap  = qb;            // alias: qb dead after Q GEMM
    float*          mk  = (float*)(Vtp + NA);

    const long total4 = (3 * NA + 4 * NW) / 4;
    const long nblk = (total4 + B_ * L_ + 255) / 256;
    cvt_mask_kernel<<<dim3((unsigned)nblk), dim3(256), 0, stream>>>(
        qx, kx, vx, Wq, Wk, Wv, Wo, ec, qb, kb, vb, wqb, wkb, wvb, wob, mk);

    // fused QKV projections (768 blocks): Q scaled, K plain, V transposed+swizzled
    GemmArgs zq = {qb, wqb, bq, Qp, 1};
    GemmArgs zk = {kb, wkb, bk, Kp, 0};
    GemmArgs zv = {vb, wvb, bv, Vtp, 2};
    gemm_kernel<64, 128><<<dim3(4, 64, 3), dim3(256), 0, stream>>>(zq, zk, zv, B_ * L_, D_, D_);

    attn_kernel<<<dim3(L_ / 64, B_ * H_), dim3(512), 0, stream>>>(Qp, Kp, Vtp, mk, Ap);

    // output projection, f32 out (512 blocks)
    GemmArgs zo = {Ap, wob, bo, out, 3};
    gemm_kernel<64, 64><<<dim3(8, 64, 1), dim3(256), 0, stream>>>(zo, zo, zo, B_ * L_, D_, D_);
}

// Round 9
// 74.549 us; speedup vs baseline: 1.2305x; 1.0106x over previous
//
#include <hip/hip_runtime.h>
#include <stdint.h>

#define B_ 2
#define L_ 2048
#define D_ 512
#define H_ 8
#define DH_ 64

using frag8 = __attribute__((ext_vector_type(8))) short;   // 8 bf16 in 4 VGPRs
using bf4   = __attribute__((ext_vector_type(4))) short;   // 4 bf16 (one b64)
using f32x4 = __attribute__((ext_vector_type(4))) float;   // MFMA accumulator
using u32x4 = __attribute__((ext_vector_type(4))) unsigned int;

#define QSC 0.18033688011112042f   /* 0.125 * log2(e): exp2-domain scale folded into Q */

__device__ __forceinline__ unsigned short f2bf(float f) {
    unsigned int u = __float_as_uint(f);
    u += 0x7fffu + ((u >> 16) & 1u);      // RNE
    return (unsigned short)(u >> 16);
}

__device__ __forceinline__ unsigned int cvtpk(float lo, float hi_) {
    unsigned int r;
    asm("v_cvt_pk_bf16_f32 %0, %1, %2" : "=v"(r) : "v"(lo), "v"(hi_));
    return r;
}

__device__ __forceinline__ void gl2lds16(const void* g, void* lds) {
    __builtin_amdgcn_global_load_lds((const __attribute__((address_space(1))) void*)g,
                                     (__attribute__((address_space(3))) void*)lds,
                                     16, 0, 0);
}

template<int N>
__device__ __forceinline__ void vmwait() {
    asm volatile("s_waitcnt vmcnt(%0)" :: "n"(N) : "memory");
}

// ---------------- prep: fp32 -> bf16 conversions + energy mask ----------------
__global__ __launch_bounds__(256) void cvt_mask_kernel(
    const float* __restrict__ qx, const float* __restrict__ kx, const float* __restrict__ vx,
    const float* __restrict__ Wq, const float* __restrict__ Wk, const float* __restrict__ Wv,
    const float* __restrict__ Wo, const float* __restrict__ ec,
    unsigned short* qb, unsigned short* kb, unsigned short* vb,
    unsigned short* wqb, unsigned short* wkb, unsigned short* wvb, unsigned short* wob,
    float* __restrict__ mk)
{
    const long NA = (long)B_ * L_ * D_;
    const long NW = (long)D_ * D_;
    const long total4 = (3 * NA + 4 * NW) / 4;
    long q4 = (long)blockIdx.x * 256 + threadIdx.x;
    if (q4 < total4) {
        long i = q4 * 4;
        const float* src; unsigned short* dst; long off;
        if (i < NA)            { src = qx; dst = qb; off = i; }
        else if (i < 2 * NA)   { src = kx; dst = kb; off = i - NA; }
        else if (i < 3 * NA)   { src = vx; dst = vb; off = i - 2 * NA; }
        else {
            long j = i - 3 * NA;
            int w = (int)(j / NW);
            off = j - (long)w * NW;
            src = (w == 0) ? Wq : (w == 1) ? Wk : (w == 2) ? Wv : Wo;
            dst = (w == 0) ? wqb : (w == 1) ? wkb : (w == 2) ? wvb : wob;
        }
        float4 v = *(const float4*)(src + off);
        ushort4 o;
        o.x = f2bf(v.x); o.y = f2bf(v.y); o.z = f2bf(v.z); o.w = f2bf(v.w);
        *(ushort4*)(dst + off) = o;
    } else {
        long i = q4 - total4;                     // 0..B*L-1 (tail blocks)
        if (i < B_ * L_) {
            const float4* p4 = (const float4*)(ec + i * 16);
            float s = 0.0f;
#pragma unroll
            for (int j = 0; j < 4; ++j) {
                float4 v = p4[j];
                s += fabsf(v.x) + fabsf(v.y) + fabsf(v.z) + fabsf(v.w);
            }
            float energy = s * (1.0f / 16.0f);
            mk[i] = (energy > 0.1f) ? 0.0f : -1.0e9f;
        }
    }
}

// ---------------- GEMM: C[M,N] = A[M,K] * W[N,K]^T + bias ----------------
// Double-buffered LDS, counted-vmcnt pipeline, raw barriers, XCD-chunked swizzle.
// mode 0: bf16 store; 1: bf16 * QSC (Q proj); 2: bf16 transposed V^T store with
// R5 slot swizzle (conflict-free b64 PV); 3: f32 store (out proj).
struct GemmArgs { const unsigned short* A; const unsigned short* W;
                  const float* bias; void* C; int mode; };

template<int BM, int BN>
__global__ __launch_bounds__(256) void gemm_kernel(GemmArgs a0, GemmArgs a1, GemmArgs a2,
                                                   int M, int N, int K)
{
    // XCD-chunked swizzle (grid size divisible by 8 by construction)
    const int nwg = gridDim.x * gridDim.y * gridDim.z;
    int flat = blockIdx.x + gridDim.x * (blockIdx.y + gridDim.y * blockIdx.z);
    int swz  = (flat & 7) * (nwg >> 3) + (flat >> 3);
    const int bx = swz % gridDim.x;
    int t2 = swz / gridDim.x;
    const int by = t2 % gridDim.y;
    const int bz = t2 / gridDim.y;

    GemmArgs ga = bz == 0 ? a0 : (bz == 1 ? a1 : a2);
    const unsigned short* __restrict__ A = ga.A;
    const unsigned short* __restrict__ W = ga.W;
    const float* __restrict__ bias = ga.bias;

    constexpr int MF = BM / 32;
    constexpr int NF = BN / 32;
    constexpr int NL = BM / 32 + BN / 32;

    __shared__ __align__(16) unsigned short As[2][BM * 64];
    __shared__ __align__(16) unsigned short Bs[2][BN * 64];

    const int tid  = threadIdx.x;
    const int lane = tid & 63;
    const int wave = tid >> 6;
    const int hi   = lane >> 4;
    const int ln   = lane & 15;
    const int wr   = wave >> 1;
    const int wc   = wave & 1;

    const long mBase = (long)by * BM;
    const long nBase = (long)bx * BN;

    f32x4 acc[MF][NF];
#pragma unroll
    for (int m = 0; m < MF; ++m)
#pragma unroll
        for (int n = 0; n < NF; ++n) acc[m][n] = (f32x4){0.f, 0.f, 0.f, 0.f};

#define GSTAGE(KT, BUF) do {                                                    \
    _Pragma("unroll")                                                           \
    for (int i_ = 0; i_ < BM / 32; ++i_) {                                      \
        int cl_ = i_ * 256 + tid;                                               \
        int r_ = cl_ >> 3, c_ = cl_ & 7, s_ = c_ ^ (r_ & 7);                    \
        gl2lds16(A + (mBase + r_) * K + (KT) + s_ * 8, As[BUF] + cl_ * 8);      \
    }                                                                           \
    _Pragma("unroll")                                                           \
    for (int i_ = 0; i_ < BN / 32; ++i_) {                                      \
        int cl_ = i_ * 256 + tid;                                               \
        int r_ = cl_ >> 3, c_ = cl_ & 7, s_ = c_ ^ (r_ & 7);                    \
        gl2lds16(W + (nBase + r_) * K + (KT) + s_ * 8, Bs[BUF] + cl_ * 8);      \
    }                                                                           \
} while (0)

    GSTAGE(0, 0);

    const int nk = K / 64;
    for (int t = 0; t < nk; ++t) {
        const int buf = t & 1;
        if (t + 1 < nk) {
            GSTAGE((t + 1) * 64, buf ^ 1);   // prefetch stays in flight across barriers
            vmwait<NL>();                     // wait only for tile t's loads
        } else {
            vmwait<0>();
        }
        __builtin_amdgcn_s_barrier();
        __builtin_amdgcn_sched_barrier(0);

        frag8 af[2][MF], bfr[2][NF];
#pragma unroll
        for (int kk = 0; kk < 2; ++kk) {
#pragma unroll
            for (int m = 0; m < MF; ++m) {
                int row = wr * (BM / 2) + m * 16 + ln;
                int c = (kk * 4 + hi) ^ (row & 7);
                af[kk][m] = *(const frag8*)(As[buf] + row * 64 + c * 8);
            }
#pragma unroll
            for (int n = 0; n < NF; ++n) {
                int row = wc * (BN / 2) + n * 16 + ln;
                int c = (kk * 4 + hi) ^ (row & 7);
                bfr[kk][n] = *(const frag8*)(Bs[buf] + row * 64 + c * 8);
            }
        }
        __builtin_amdgcn_s_setprio(1);
#pragma unroll
        for (int kk = 0; kk < 2; ++kk)
#pragma unroll
            for (int m = 0; m < MF; ++m)
#pragma unroll
                for (int n = 0; n < NF; ++n)
                    acc[m][n] = __builtin_amdgcn_mfma_f32_16x16x32_bf16(af[kk][m], bfr[kk][n], acc[m][n], 0, 0, 0);
        __builtin_amdgcn_s_setprio(0);
        __builtin_amdgcn_sched_barrier(0);
        __builtin_amdgcn_s_barrier();        // raw: prefetch stays in flight
    }
#undef GSTAGE

    const int mode = ga.mode;
#pragma unroll
    for (int m = 0; m < MF; ++m) {
#pragma unroll
        for (int n = 0; n < NF; ++n) {
            long col = nBase + wc * (BN / 2) + n * 16 + ln;
            float bv = bias[col];
#pragma unroll
            for (int j = 0; j < 4; ++j) {
                long row = mBase + wr * (BM / 2) + m * 16 + hi * 4 + j;
                float v = acc[m][n][j] + bv;
                if (mode == 3) {
                    ((float*)ga.C)[row * N + col] = v;
                } else if (mode == 2) {
                    // V^T store: R5 slot swizzle (key-group s at s^sw within 64)
                    int dh = (int)col & 63;
                    int swv = ((dh & 7) << 1) | ((dh >> 3) & 1);
                    long nt = (row & ~63L) | (long)(((((int)(row >> 2)) & 15) ^ swv) << 2) | (row & 3);
                    ((unsigned short*)ga.C)[col * (long)(B_ * L_) + nt] = f2bf(v);
                } else {
                    if (mode == 1) v *= QSC;
                    ((unsigned short*)ga.C)[row * N + col] = f2bf(v);
                }
            }
        }
    }
}

// ---------------- fused flash attention ----------------
// grid (L/64, B*H), 512 thr = 8 waves; groups 0/1 = even/odd 64-key tiles, each
// double-buffers K/V in LDS. DEFERRED softmax/PV schedule, ONE barrier per iter:
//   softmax(i-1)+PV(i-1) [V(i-1) valid since barrier(i-1)]
//   vmwait(0); barrier   [buf(i) staged everywhere; all waves done with buf^1]
//   STAGE(i+1 -> buf^1)  [~500cy hiding window until barrier(i+1)]
//   QK^T(i); scp = sv + mask
// Q pre-scaled by 0.125*log2e (exp2-domain), defer-max THR=8, max3 trees.
// V^T slot-swizzled in global (R5 layout): conflict-free b64 PV reads.
__global__ __launch_bounds__(512, 4) void attn_kernel(
    const unsigned short* __restrict__ Qg, const unsigned short* __restrict__ Kg,
    const unsigned short* __restrict__ Vt, const float* __restrict__ mkg,
    unsigned short* __restrict__ Og)
{
    const int tid  = threadIdx.x;
    const int lane = tid & 63;
    const int wave = tid >> 6;
    const int grp  = wave >> 2;
    const int wq   = wave & 3;
    const int gtid = tid & 255;
    const int hi   = lane >> 4;
    const int ln   = lane & 15;

    const int bh = blockIdx.y;
    const int b  = bh >> 3, h = bh & 7;
    const unsigned short* Qb = Qg + ((long)b * L_) * D_ + h * DH_;
    const unsigned short* Kb = Kg + ((long)b * L_) * D_ + h * DH_;
    const unsigned short* Vb = Vt + (long)(h * DH_) * (B_ * L_) + (long)b * L_;
    const float* mkb = mkg + (long)b * L_;

    __shared__ __align__(16) char smem[65536];
    unsigned short* KsG = (unsigned short*)(smem + grp * 32768);
    unsigned short* VsG = (unsigned short*)(smem + grp * 32768 + 16384);

    const int q0 = blockIdx.x * 64 + wq * 16;

    frag8 qf[2];
#pragma unroll
    for (int ks = 0; ks < 2; ++ks)
        qf[ks] = *(const frag8*)(Qb + (long)(q0 + ln) * D_ + ks * 32 + hi * 8);

    // hoisted PV slot offsets (V^T global swizzle: group s stored at s^sw)
    const int sw  = ((ln & 7) << 1) | ((ln >> 3) & 1);
    const int sl0 = ((hi     ) ^ sw) << 2;
    const int sl1 = ((hi + 4 ) ^ sw) << 2;
    const int sl2 = ((hi + 8 ) ^ sw) << 2;
    const int sl3 = ((hi + 12) ^ sw) << 2;

#define STAGE(TT, BUF) do {                                                     \
    _Pragma("unroll")                                                           \
    for (int c2_ = 0; c2_ < 2; ++c2_) {                                         \
        int cl_ = c2_ * 256 + gtid;                                             \
        int r_ = cl_ >> 3, c_ = cl_ & 7;                                        \
        gl2lds16(Kb + (long)((TT) * 64 + r_) * D_ + ((c_ ^ (r_ & 7)) << 3),     \
                 KsG + (BUF) * 4096 + cl_ * 8);                                 \
        gl2lds16(Vb + (long)r_ * (B_ * L_) + (TT) * 64 + (c_ << 3),             \
                 VsG + (BUF) * 4096 + cl_ * 8);                                 \
    }                                                                           \
} while (0)

    f32x4 o[4];
#pragma unroll
    for (int g = 0; g < 4; ++g) o[g] = (f32x4){0.f, 0.f, 0.f, 0.f};
    float m_run = -__builtin_inff();
    float l_run = 0.0f;
    float scp[16];          // deferred scores (previous tile)

    // deferred softmax + PV on scp, V from Vl
    auto SOFTPV = [&](const unsigned short* Vl) {
        // max tree (max3-friendly nesting)
        float a0 = fmaxf(fmaxf(scp[0], scp[1]), scp[2]);
        float a1 = fmaxf(fmaxf(scp[3], scp[4]), scp[5]);
        float a2 = fmaxf(fmaxf(scp[6], scp[7]), scp[8]);
        float a3 = fmaxf(fmaxf(scp[9], scp[10]), scp[11]);
        float a4 = fmaxf(fmaxf(scp[12], scp[13]), scp[14]);
        float tl = fmaxf(fmaxf(fmaxf(a0, a1), a2), fmaxf(fmaxf(a3, a4), scp[15]));
        float tmax = fmaxf(tl, __shfl_xor(tl, 16));
        tmax = fmaxf(tmax, __shfl_xor(tmax, 32));

        // defer-max (T13): rescale only if max grew by > 8 (exp2 dom: p <= 256)
        if (!__all(tmax <= m_run + 8.0f)) {
            float m_new = fmaxf(m_run, tmax);
            float alpha = __builtin_amdgcn_exp2f(m_run - m_new);
            float b0 = __shfl(alpha, 4 * hi + 0);
            float b1 = __shfl(alpha, 4 * hi + 1);
            float b2 = __shfl(alpha, 4 * hi + 2);
            float b3 = __shfl(alpha, 4 * hi + 3);
#pragma unroll
            for (int g = 0; g < 4; ++g) {
                o[g][0] *= b0; o[g][1] *= b1; o[g][2] *= b2; o[g][3] *= b3;
            }
            l_run *= alpha;
            m_run = m_new;
        }

        float p[16];
#pragma unroll
        for (int j = 0; j < 16; ++j) p[j] = __builtin_amdgcn_exp2f(scp[j] - m_run);
        float s01 = (p[0] + p[1]) + (p[2] + p[3]);
        float s23 = (p[4] + p[5]) + (p[6] + p[7]);
        float s45 = (p[8] + p[9]) + (p[10] + p[11]);
        float s67 = (p[12] + p[13]) + (p[14] + p[15]);
        float ps = (s01 + s23) + (s45 + s67);
        ps += __shfl_xor(ps, 16);
        ps += __shfl_xor(ps, 32);
        l_run += ps;

        union PU { u32x4 u; frag8 f; } p0u, p1u;
        p0u.u = (u32x4){cvtpk(p[0], p[1]),  cvtpk(p[2], p[3]),
                        cvtpk(p[4], p[5]),  cvtpk(p[6], p[7])};
        p1u.u = (u32x4){cvtpk(p[8], p[9]),  cvtpk(p[10], p[11]),
                        cvtpk(p[12], p[13]), cvtpk(p[14], p[15])};

        __builtin_amdgcn_s_setprio(1);
#pragma unroll
        for (int g = 0; g < 4; ++g) {
            int rowb = (g * 16 + ln) * 64;
            bf4 v0 = *(const bf4*)(Vl + rowb + sl0);
            bf4 v1 = *(const bf4*)(Vl + rowb + sl1);
            bf4 v2 = *(const bf4*)(Vl + rowb + sl2);
            bf4 v3 = *(const bf4*)(Vl + rowb + sl3);
            frag8 vf0 = __builtin_shufflevector(v0, v1, 0, 1, 2, 3, 4, 5, 6, 7);
            frag8 vf1 = __builtin_shufflevector(v2, v3, 0, 1, 2, 3, 4, 5, 6, 7);
            o[g] = __builtin_amdgcn_mfma_f32_16x16x32_bf16(p0u.f, vf0, o[g], 0, 0, 0);
            o[g] = __builtin_amdgcn_mfma_f32_16x16x32_bf16(p1u.f, vf1, o[g], 0, 0, 0);
        }
        __builtin_amdgcn_s_setprio(0);
    };

    // QK^T of tile (buf) + save masked scores into scp
    auto QKSAVE = [&](const unsigned short* Kl, int T) {
        float4 m40 = *(const float4*)(mkb + T * 64 +      4 * hi);
        float4 m41 = *(const float4*)(mkb + T * 64 + 16 + 4 * hi);
        float4 m42 = *(const float4*)(mkb + T * 64 + 32 + 4 * hi);
        float4 m43 = *(const float4*)(mkb + T * 64 + 48 + 4 * hi);
        f32x4 sv[4];
#pragma unroll
        for (int sh = 0; sh < 4; ++sh) sv[sh] = (f32x4){0.f, 0.f, 0.f, 0.f};
        __builtin_amdgcn_s_setprio(1);
#pragma unroll
        for (int sh = 0; sh < 4; ++sh) {
            int key = sh * 16 + ln;
#pragma unroll
            for (int ks = 0; ks < 2; ++ks) {
                frag8 kf = *(const frag8*)(Kl + key * 64 + (((ks * 4 + hi) ^ (ln & 7)) << 3));
                sv[sh] = __builtin_amdgcn_mfma_f32_16x16x32_bf16(kf, qf[ks], sv[sh], 0, 0, 0);
            }
        }
        __builtin_amdgcn_s_setprio(0);
        scp[0]  = sv[0][0] + m40.x; scp[1]  = sv[0][1] + m40.y;
        scp[2]  = sv[0][2] + m40.z; scp[3]  = sv[0][3] + m40.w;
        scp[4]  = sv[1][0] + m41.x; scp[5]  = sv[1][1] + m41.y;
        scp[6]  = sv[1][2] + m41.z; scp[7]  = sv[1][3] + m41.w;
        scp[8]  = sv[2][0] + m42.x; scp[9]  = sv[2][1] + m42.y;
        scp[10] = sv[2][2] + m42.z; scp[11] = sv[2][3] + m42.w;
        scp[12] = sv[3][0] + m43.x; scp[13] = sv[3][1] + m43.y;
        scp[14] = sv[3][2] + m43.z; scp[15] = sv[3][3] + m43.w;
    };

    // ---- iteration 0 (peeled): no deferred work ----
    STAGE(grp, 0);
    vmwait<0>();
    __builtin_amdgcn_s_barrier();
    __builtin_amdgcn_sched_barrier(0);
    STAGE(2 + grp, 1);
    QKSAVE(KsG, grp);

    // ---- steady state ----
    for (int i = 1; i < 16; ++i) {
        const int buf = i & 1;
        SOFTPV(VsG + (buf ^ 1) * 4096);       // tile i-1 (V valid until STAGE below)
        vmwait<0>();
        __builtin_amdgcn_s_barrier();          // buf(i) ready; all done with buf^1
        __builtin_amdgcn_sched_barrier(0);
        if (i < 15) STAGE(2 * (i + 1) + grp, buf ^ 1);
        QKSAVE(KsG + buf * 4096, 2 * i + grp);
    }
    // ---- epilogue: tile 15 (V in buf 1, untouched) ----
    SOFTPV(VsG + 4096);
#undef STAGE

    // ---- merge group 1 partials into group 0, write out ----
    __syncthreads();
    float* oX = (float*)smem;                       // [64][68] padded f32
    float* mX = (float*)(smem + 64 * 68 * 4);       // [64]
    float* lX = mX + 64;

    if (grp == 1) {
#pragma unroll
        for (int g = 0; g < 4; ++g)
#pragma unroll
            for (int j = 0; j < 4; ++j)
                oX[(wq * 16 + 4 * hi + j) * 68 + g * 16 + ln] = o[g][j];
        if (hi == 0) { mX[wq * 16 + ln] = m_run; lX[wq * 16 + ln] = l_run; }
    }
    __syncthreads();
    if (grp == 0) {
#pragma unroll
        for (int j = 0; j < 4; ++j) {
            int q = 4 * hi + j;
            float mA = __shfl(m_run, q);
            float lA = __shfl(l_run, q);
            float mB = mX[wq * 16 + q];
            float lB = lX[wq * 16 + q];
            float mm = fmaxf(mA, mB);
            float aA = __builtin_amdgcn_exp2f(mA - mm);
            float aB = __builtin_amdgcn_exp2f(mB - mm);
            float inv = 1.0f / (lA * aA + lB * aB);
            aA *= inv; aB *= inv;
#pragma unroll
            for (int g = 0; g < 4; ++g) {
                float v = o[g][j] * aA + oX[(wq * 16 + q) * 68 + g * 16 + ln] * aB;
                long idx = ((long)b * L_ + q0 + q) * D_ + h * DH_ + g * 16 + ln;
                Og[idx] = f2bf(v);
            }
        }
    }
}

// ---------------- launch ----------------
extern "C" void kernel_launch(void* const* d_in, const int* in_sizes, int n_in,
                              void* d_out, int out_size, void* d_ws, size_t ws_size,
                              hipStream_t stream)
{
    const float* qx = (const float*)d_in[0];
    const float* kx = (const float*)d_in[1];
    const float* vx = (const float*)d_in[2];
    const float* ec = (const float*)d_in[3];
    const float* Wq = (const float*)d_in[4];
    const float* bq = (const float*)d_in[5];
    const float* Wk = (const float*)d_in[6];
    const float* bk = (const float*)d_in[7];
    const float* Wv = (const float*)d_in[8];
    const float* bv = (const float*)d_in[9];
    const float* Wo = (const float*)d_in[10];
    const float* bo = (const float*)d_in[11];
    float* out = (float*)d_out;

    const long NA = (long)B_ * L_ * D_;
    const long NW = (long)D_ * D_;

    unsigned short* qb  = (unsigned short*)d_ws;
    unsigned short* kb  = qb + NA;
    unsigned short* vb  = kb + NA;
    unsigned short* wqb = vb + NA;
    unsigned short* wkb = wqb + NW;
    unsigned short* wvb = wkb + NW;
    unsigned short* wob = wvb + NW;
    unsigned short* Qp  = wob + NW;
    unsigned short* Kp  = Qp + NA;
    unsigned short* Vtp = Kp + NA;       // V^T: [D][B*L], slot-swizzled
    unsigned short* Ap  = qb;            // alias: qb dead after Q GEMM
    float*          mk  = (float*)(Vtp + NA);

    const long total4 = (3 * NA + 4 * NW) / 4;
    const long nblk = (total4 + B_ * L_ + 255) / 256;
    cvt_mask_kernel<<<dim3((unsigned)nblk), dim3(256), 0, stream>>>(
        qx, kx, vx, Wq, Wk, Wv, Wo, ec, qb, kb, vb, wqb, wkb, wvb, wob, mk);

    // fused QKV projections (768 blocks): Q scaled, K plain, V transposed+swizzled
    GemmArgs zq = {qb, wqb, bq, Qp, 1};
    GemmArgs zk = {kb, wkb, bk, Kp, 0};
    GemmArgs zv = {vb, wvb, bv, Vtp, 2};
    gemm_kernel<64, 128><<<dim3(4, 64, 3), dim3(256), 0, stream>>>(zq, zk, zv, B_ * L_, D_, D_);

    attn_kernel<<<dim3(L_ / 64, B_ * H_), dim3(512), 0, stream>>>(Qp, Kp, Vtp, mk, Ap);

    // output projection, f32 out (512 blocks)
    GemmArgs zo = {Ap, wob, bo, out, 3};
    gemm_kernel<64, 64><<<dim3(8, 64, 1), dim3(256), 0, stream>>>(zo, zo, zo, B_ * L_, D_, D_);
}

// Round 10
// 74.337 us; speedup vs baseline: 1.2340x; 1.0028x over previous
//
#include <hip/hip_runtime.h>
#include <stdint.h>

#define B_ 2
#define L_ 2048
#define D_ 512
#define H_ 8
#define DH_ 64

using frag8 = __attribute__((ext_vector_type(8))) short;   // 8 bf16 in 4 VGPRs
using bf4   = __attribute__((ext_vector_type(4))) short;   // 4 bf16 (one b64)
using f32x4 = __attribute__((ext_vector_type(4))) float;   // MFMA accumulator
using u32x4 = __attribute__((ext_vector_type(4))) unsigned int;

#define QSC 0.18033688011112042f   /* 0.125 * log2(e): exp2-domain scale folded into Q */

__device__ __forceinline__ unsigned short f2bf(float f) {
    unsigned int u = __float_as_uint(f);
    u += 0x7fffu + ((u >> 16) & 1u);      // RNE
    return (unsigned short)(u >> 16);
}

__device__ __forceinline__ unsigned int cvtpk(float lo, float hi_) {
    unsigned int r;
    asm("v_cvt_pk_bf16_f32 %0, %1, %2" : "=v"(r) : "v"(lo), "v"(hi_));
    return r;
}

__device__ __forceinline__ void gl2lds16(const void* g, void* lds) {
    __builtin_amdgcn_global_load_lds((const __attribute__((address_space(1))) void*)g,
                                     (__attribute__((address_space(3))) void*)lds,
                                     16, 0, 0);
}

template<int N>
__device__ __forceinline__ void vmwait() {
    asm volatile("s_waitcnt vmcnt(%0)" :: "n"(N) : "memory");
}

// ---------------- prep: fp32 -> bf16 conversions + energy mask ----------------
__global__ __launch_bounds__(256) void cvt_mask_kernel(
    const float* __restrict__ qx, const float* __restrict__ kx, const float* __restrict__ vx,
    const float* __restrict__ Wq, const float* __restrict__ Wk, const float* __restrict__ Wv,
    const float* __restrict__ Wo, const float* __restrict__ ec,
    unsigned short* qb, unsigned short* kb, unsigned short* vb,
    unsigned short* wqb, unsigned short* wkb, unsigned short* wvb, unsigned short* wob,
    float* __restrict__ mk)
{
    const long NA = (long)B_ * L_ * D_;
    const long NW = (long)D_ * D_;
    const long total4 = (3 * NA + 4 * NW) / 4;
    long q4 = (long)blockIdx.x * 256 + threadIdx.x;
    if (q4 < total4) {
        long i = q4 * 4;
        const float* src; unsigned short* dst; long off;
        if (i < NA)            { src = qx; dst = qb; off = i; }
        else if (i < 2 * NA)   { src = kx; dst = kb; off = i - NA; }
        else if (i < 3 * NA)   { src = vx; dst = vb; off = i - 2 * NA; }
        else {
            long j = i - 3 * NA;
            int w = (int)(j / NW);
            off = j - (long)w * NW;
            src = (w == 0) ? Wq : (w == 1) ? Wk : (w == 2) ? Wv : Wo;
            dst = (w == 0) ? wqb : (w == 1) ? wkb : (w == 2) ? wvb : wob;
        }
        float4 v = *(const float4*)(src + off);
        ushort4 o;
        o.x = f2bf(v.x); o.y = f2bf(v.y); o.z = f2bf(v.z); o.w = f2bf(v.w);
        *(ushort4*)(dst + off) = o;
    } else {
        long i = q4 - total4;                     // 0..B*L-1 (tail blocks)
        if (i < B_ * L_) {
            const float4* p4 = (const float4*)(ec + i * 16);
            float s = 0.0f;
#pragma unroll
            for (int j = 0; j < 4; ++j) {
                float4 v = p4[j];
                s += fabsf(v.x) + fabsf(v.y) + fabsf(v.z) + fabsf(v.w);
            }
            float energy = s * (1.0f / 16.0f);
            mk[i] = (energy > 0.1f) ? 0.0f : -1.0e9f;
        }
    }
}

// ---------------- GEMM: C[M,N] = A[M,K] * W[N,K]^T + bias ----------------
// Double-buffered LDS, counted-vmcnt pipeline, raw barriers, XCD-chunked swizzle,
// bias as MFMA C-init.
// mode 0: bf16 store; 1: bf16 * QSC (Q proj); 2: bf16 transposed V^T store with
// R5 slot swizzle (conflict-free b64 PV); 3: f32 store (out proj).
struct GemmArgs { const unsigned short* A; const unsigned short* W;
                  const float* bias; void* C; int mode; };

template<int BM, int BN>
__global__ __launch_bounds__(256) void gemm_kernel(GemmArgs a0, GemmArgs a1, GemmArgs a2,
                                                   int M, int N, int K)
{
    // XCD-chunked swizzle (grid size divisible by 8 by construction)
    const int nwg = gridDim.x * gridDim.y * gridDim.z;
    int flat = blockIdx.x + gridDim.x * (blockIdx.y + gridDim.y * blockIdx.z);
    int swz  = (flat & 7) * (nwg >> 3) + (flat >> 3);
    const int bx = swz % gridDim.x;
    int t2 = swz / gridDim.x;
    const int by = t2 % gridDim.y;
    const int bz = t2 / gridDim.y;

    GemmArgs ga = bz == 0 ? a0 : (bz == 1 ? a1 : a2);
    const unsigned short* __restrict__ A = ga.A;
    const unsigned short* __restrict__ W = ga.W;
    const float* __restrict__ bias = ga.bias;

    constexpr int MF = BM / 32;
    constexpr int NF = BN / 32;
    constexpr int NL = BM / 32 + BN / 32;

    __shared__ __align__(16) unsigned short As[2][BM * 64];
    __shared__ __align__(16) unsigned short Bs[2][BN * 64];

    const int tid  = threadIdx.x;
    const int lane = tid & 63;
    const int wave = tid >> 6;
    const int hi   = lane >> 4;
    const int ln   = lane & 15;
    const int wr   = wave >> 1;
    const int wc   = wave & 1;

    const long mBase = (long)by * BM;
    const long nBase = (long)bx * BN;

    // bias as C-init (per output column)
    f32x4 acc[MF][NF];
#pragma unroll
    for (int n = 0; n < NF; ++n) {
        float bv = bias[nBase + wc * (BN / 2) + n * 16 + ln];
#pragma unroll
        for (int m = 0; m < MF; ++m) acc[m][n] = (f32x4){bv, bv, bv, bv};
    }

#define GSTAGE(KT, BUF) do {                                                    \
    _Pragma("unroll")                                                           \
    for (int i_ = 0; i_ < BM / 32; ++i_) {                                      \
        int cl_ = i_ * 256 + tid;                                               \
        int r_ = cl_ >> 3, c_ = cl_ & 7, s_ = c_ ^ (r_ & 7);                    \
        gl2lds16(A + (mBase + r_) * K + (KT) + s_ * 8, As[BUF] + cl_ * 8);      \
    }                                                                           \
    _Pragma("unroll")                                                           \
    for (int i_ = 0; i_ < BN / 32; ++i_) {                                      \
        int cl_ = i_ * 256 + tid;                                               \
        int r_ = cl_ >> 3, c_ = cl_ & 7, s_ = c_ ^ (r_ & 7);                    \
        gl2lds16(W + (nBase + r_) * K + (KT) + s_ * 8, Bs[BUF] + cl_ * 8);      \
    }                                                                           \
} while (0)

    GSTAGE(0, 0);

    const int nk = K / 64;
    for (int t = 0; t < nk; ++t) {
        const int buf = t & 1;
        if (t + 1 < nk) {
            GSTAGE((t + 1) * 64, buf ^ 1);   // prefetch stays in flight across barriers
            vmwait<NL>();                     // wait only for tile t's loads
        } else {
            vmwait<0>();
        }
        __builtin_amdgcn_s_barrier();
        __builtin_amdgcn_sched_barrier(0);

        frag8 af[2][MF], bfr[2][NF];
#pragma unroll
        for (int kk = 0; kk < 2; ++kk) {
#pragma unroll
            for (int m = 0; m < MF; ++m) {
                int row = wr * (BM / 2) + m * 16 + ln;
                int c = (kk * 4 + hi) ^ (row & 7);
                af[kk][m] = *(const frag8*)(As[buf] + row * 64 + c * 8);
            }
#pragma unroll
            for (int n = 0; n < NF; ++n) {
                int row = wc * (BN / 2) + n * 16 + ln;
                int c = (kk * 4 + hi) ^ (row & 7);
                bfr[kk][n] = *(const frag8*)(Bs[buf] + row * 64 + c * 8);
            }
        }
        __builtin_amdgcn_s_setprio(1);
#pragma unroll
        for (int kk = 0; kk < 2; ++kk)
#pragma unroll
            for (int m = 0; m < MF; ++m)
#pragma unroll
                for (int n = 0; n < NF; ++n)
                    acc[m][n] = __builtin_amdgcn_mfma_f32_16x16x32_bf16(af[kk][m], bfr[kk][n], acc[m][n], 0, 0, 0);
        __builtin_amdgcn_s_setprio(0);
        __builtin_amdgcn_sched_barrier(0);
        __builtin_amdgcn_s_barrier();        // raw: prefetch stays in flight
    }
#undef GSTAGE

    const int mode = ga.mode;
#pragma unroll
    for (int m = 0; m < MF; ++m) {
#pragma unroll
        for (int n = 0; n < NF; ++n) {
            long col = nBase + wc * (BN / 2) + n * 16 + ln;
#pragma unroll
            for (int j = 0; j < 4; ++j) {
                long row = mBase + wr * (BM / 2) + m * 16 + hi * 4 + j;
                float v = acc[m][n][j];
                if (mode == 3) {
                    ((float*)ga.C)[row * N + col] = v;
                } else if (mode == 2) {
                    // V^T store: R5 slot swizzle (key-group s at s^sw within 64)
                    int dh = (int)col & 63;
                    int swv = ((dh & 7) << 1) | ((dh >> 3) & 1);
                    long nt = (row & ~63L) | (long)(((((int)(row >> 2)) & 15) ^ swv) << 2) | (row & 3);
                    ((unsigned short*)ga.C)[col * (long)(B_ * L_) + nt] = f2bf(v);
                } else {
                    if (mode == 1) v *= QSC;
                    ((unsigned short*)ga.C)[row * N + col] = f2bf(v);
                }
            }
        }
    }
}

// ---------------- fused flash attention ----------------
// grid (L/64, B*H), 512 thr = 8 waves; groups 0/1 = even/odd 64-key tiles, each
// double-buffers K/V in LDS. DEFERRED softmax/PV schedule, ONE barrier per iter.
// Mask enters as the MFMA C-init (prefetched one tile ahead); softmax in exp2
// domain (Q pre-scaled by 0.125*log2e), defer-max THR=8, 3-way butterfly
// reduces. V^T slot-swizzled in global: conflict-free b64 PV reads.
__global__ __launch_bounds__(512, 4) void attn_kernel(
    const unsigned short* __restrict__ Qg, const unsigned short* __restrict__ Kg,
    const unsigned short* __restrict__ Vt, const float* __restrict__ mkg,
    unsigned short* __restrict__ Og)
{
    const int tid  = threadIdx.x;
    const int lane = tid & 63;
    const int wave = tid >> 6;
    const int grp  = wave >> 2;
    const int wq   = wave & 3;
    const int gtid = tid & 255;
    const int hi   = lane >> 4;
    const int ln   = lane & 15;

    const int bh = blockIdx.y;
    const int b  = bh >> 3, h = bh & 7;
    const unsigned short* Qb = Qg + ((long)b * L_) * D_ + h * DH_;
    const unsigned short* Kb = Kg + ((long)b * L_) * D_ + h * DH_;
    const unsigned short* Vb = Vt + (long)(h * DH_) * (B_ * L_) + (long)b * L_;
    const float* mkb = mkg + (long)b * L_;

    __shared__ __align__(16) char smem[65536];
    unsigned short* KsG = (unsigned short*)(smem + grp * 32768);
    unsigned short* VsG = (unsigned short*)(smem + grp * 32768 + 16384);

    const int q0 = blockIdx.x * 64 + wq * 16;

    frag8 qf[2];
#pragma unroll
    for (int ks = 0; ks < 2; ++ks)
        qf[ks] = *(const frag8*)(Qb + (long)(q0 + ln) * D_ + ks * 32 + hi * 8);

    // hoisted PV slot offsets (V^T global swizzle: group s stored at s^sw)
    const int sw  = ((ln & 7) << 1) | ((ln >> 3) & 1);
    const int sl0 = ((hi     ) ^ sw) << 2;
    const int sl1 = ((hi + 4 ) ^ sw) << 2;
    const int sl2 = ((hi + 8 ) ^ sw) << 2;
    const int sl3 = ((hi + 12) ^ sw) << 2;

#define STAGE(TT, BUF) do {                                                     \
    _Pragma("unroll")                                                           \
    for (int c2_ = 0; c2_ < 2; ++c2_) {                                         \
        int cl_ = c2_ * 256 + gtid;                                             \
        int r_ = cl_ >> 3, c_ = cl_ & 7;                                        \
        gl2lds16(Kb + (long)((TT) * 64 + r_) * D_ + ((c_ ^ (r_ & 7)) << 3),     \
                 KsG + (BUF) * 4096 + cl_ * 8);                                 \
        gl2lds16(Vb + (long)r_ * (B_ * L_) + (TT) * 64 + (c_ << 3),             \
                 VsG + (BUF) * 4096 + cl_ * 8);                                 \
    }                                                                           \
} while (0)

#define LOADM(TT, A0, A1, A2, A3) do {                                          \
    A0 = *(const f32x4*)(mkb + (TT) * 64 +      4 * hi);                        \
    A1 = *(const f32x4*)(mkb + (TT) * 64 + 16 + 4 * hi);                        \
    A2 = *(const f32x4*)(mkb + (TT) * 64 + 32 + 4 * hi);                        \
    A3 = *(const f32x4*)(mkb + (TT) * 64 + 48 + 4 * hi);                        \
} while (0)

    f32x4 o[4];
#pragma unroll
    for (int g = 0; g < 4; ++g) o[g] = (f32x4){0.f, 0.f, 0.f, 0.f};
    float m_run = -__builtin_inff();
    float l_run = 0.0f;
    f32x4 scp[4];                 // deferred masked scores (previous tile)
    f32x4 mc0, mc1, mc2, mc3;     // mask: current tile (C-init)
    f32x4 mn0, mn1, mn2, mn3;     // mask: prefetched next tile

    // deferred softmax + PV on scp, V from Vl
    auto SOFTPV = [&](const unsigned short* Vl) {
        float a0 = fmaxf(fmaxf(scp[0][0], scp[0][1]), fmaxf(scp[0][2], scp[0][3]));
        float a1 = fmaxf(fmaxf(scp[1][0], scp[1][1]), fmaxf(scp[1][2], scp[1][3]));
        float a2 = fmaxf(fmaxf(scp[2][0], scp[2][1]), fmaxf(scp[2][2], scp[2][3]));
        float a3 = fmaxf(fmaxf(scp[3][0], scp[3][1]), fmaxf(scp[3][2], scp[3][3]));
        float tl = fmaxf(fmaxf(a0, a1), fmaxf(a2, a3));
        float tA = __shfl_xor(tl, 16);
        float tB = __shfl_xor(tl, 32);
        float tC = __shfl_xor(tl, 48);
        float tmax = fmaxf(fmaxf(tl, tA), fmaxf(tB, tC));

        // defer-max (T13): rescale only if max grew by > 8 (exp2 dom: p <= 256)
        if (!__all(tmax <= m_run + 8.0f)) {
            float m_new = fmaxf(m_run, tmax);
            float alpha = __builtin_amdgcn_exp2f(m_run - m_new);
            float b0 = __shfl(alpha, 4 * hi + 0);
            float b1 = __shfl(alpha, 4 * hi + 1);
            float b2 = __shfl(alpha, 4 * hi + 2);
            float b3 = __shfl(alpha, 4 * hi + 3);
#pragma unroll
            for (int g = 0; g < 4; ++g) {
                o[g][0] *= b0; o[g][1] *= b1; o[g][2] *= b2; o[g][3] *= b3;
            }
            l_run *= alpha;
            m_run = m_new;
        }

        float p[16];
#pragma unroll
        for (int sh = 0; sh < 4; ++sh)
#pragma unroll
            for (int r = 0; r < 4; ++r)
                p[sh * 4 + r] = __builtin_amdgcn_exp2f(scp[sh][r] - m_run);
        float s01 = (p[0] + p[1]) + (p[2] + p[3]);
        float s23 = (p[4] + p[5]) + (p[6] + p[7]);
        float s45 = (p[8] + p[9]) + (p[10] + p[11]);
        float s67 = (p[12] + p[13]) + (p[14] + p[15]);
        float ps = (s01 + s23) + (s45 + s67);
        float pA = __shfl_xor(ps, 16);
        float pB = __shfl_xor(ps, 32);
        float pC = __shfl_xor(ps, 48);
        l_run += (ps + pA) + (pB + pC);

        union PU { u32x4 u; frag8 f; } p0u, p1u;
        p0u.u = (u32x4){cvtpk(p[0], p[1]),  cvtpk(p[2], p[3]),
                        cvtpk(p[4], p[5]),  cvtpk(p[6], p[7])};
        p1u.u = (u32x4){cvtpk(p[8], p[9]),  cvtpk(p[10], p[11]),
                        cvtpk(p[12], p[13]), cvtpk(p[14], p[15])};

        __builtin_amdgcn_s_setprio(1);
#pragma unroll
        for (int g = 0; g < 4; ++g) {
            int rowb = (g * 16 + ln) * 64;
            bf4 v0 = *(const bf4*)(Vl + rowb + sl0);
            bf4 v1 = *(const bf4*)(Vl + rowb + sl1);
            bf4 v2 = *(const bf4*)(Vl + rowb + sl2);
            bf4 v3 = *(const bf4*)(Vl + rowb + sl3);
            frag8 vf0 = __builtin_shufflevector(v0, v1, 0, 1, 2, 3, 4, 5, 6, 7);
            frag8 vf1 = __builtin_shufflevector(v2, v3, 0, 1, 2, 3, 4, 5, 6, 7);
            o[g] = __builtin_amdgcn_mfma_f32_16x16x32_bf16(p0u.f, vf0, o[g], 0, 0, 0);
            o[g] = __builtin_amdgcn_mfma_f32_16x16x32_bf16(p1u.f, vf1, o[g], 0, 0, 0);
        }
        __builtin_amdgcn_s_setprio(0);
    };

    // QK^T of tile in Kl; mask (mc*) enters as MFMA C-init; result -> scp
    auto QKSAVE = [&](const unsigned short* Kl) {
        scp[0] = mc0; scp[1] = mc1; scp[2] = mc2; scp[3] = mc3;
        __builtin_amdgcn_s_setprio(1);
#pragma unroll
        for (int sh = 0; sh < 4; ++sh) {
            int key = sh * 16 + ln;
#pragma unroll
            for (int ks = 0; ks < 2; ++ks) {
                frag8 kf = *(const frag8*)(Kl + key * 64 + (((ks * 4 + hi) ^ (ln & 7)) << 3));
                scp[sh] = __builtin_amdgcn_mfma_f32_16x16x32_bf16(kf, qf[ks], scp[sh], 0, 0, 0);
            }
        }
        __builtin_amdgcn_s_setprio(0);
    };

    // ---- iteration 0 (peeled) ----
    STAGE(grp, 0);
    LOADM(grp, mc0, mc1, mc2, mc3);
    vmwait<0>();
    __builtin_amdgcn_s_barrier();
    __builtin_amdgcn_sched_barrier(0);
    STAGE(2 + grp, 1);
    LOADM(2 + grp, mn0, mn1, mn2, mn3);
    QKSAVE(KsG);

    // ---- steady state ----
    for (int i = 1; i < 16; ++i) {
        const int buf = i & 1;
        SOFTPV(VsG + (buf ^ 1) * 4096);       // tile i-1 (V valid until STAGE below)
        vmwait<0>();
        __builtin_amdgcn_s_barrier();          // buf(i) ready; all done with buf^1
        __builtin_amdgcn_sched_barrier(0);
        if (i < 15) STAGE(2 * (i + 1) + grp, buf ^ 1);
        mc0 = mn0; mc1 = mn1; mc2 = mn2; mc3 = mn3;
        if (i < 15) LOADM(2 * (i + 1) + grp, mn0, mn1, mn2, mn3);
        QKSAVE(KsG + buf * 4096);
    }
    // ---- epilogue: tile 15 (V in buf 1, untouched) ----
    SOFTPV(VsG + 4096);
#undef STAGE
#undef LOADM

    // ---- merge group 1 partials into group 0, write out ----
    __syncthreads();
    float* oX = (float*)smem;                       // [64][68] padded f32
    float* mX = (float*)(smem + 64 * 68 * 4);       // [64]
    float* lX = mX + 64;

    if (grp == 1) {
#pragma unroll
        for (int g = 0; g < 4; ++g)
#pragma unroll
            for (int j = 0; j < 4; ++j)
                oX[(wq * 16 + 4 * hi + j) * 68 + g * 16 + ln] = o[g][j];
        if (hi == 0) { mX[wq * 16 + ln] = m_run; lX[wq * 16 + ln] = l_run; }
    }
    __syncthreads();
    if (grp == 0) {
#pragma unroll
        for (int j = 0; j < 4; ++j) {
            int q = 4 * hi + j;
            float mA = __shfl(m_run, q);
            float lA = __shfl(l_run, q);
            float mB = mX[wq * 16 + q];
            float lB = lX[wq * 16 + q];
            float mm = fmaxf(mA, mB);
            float aA = __builtin_amdgcn_exp2f(mA - mm);
            float aB = __builtin_amdgcn_exp2f(mB - mm);
            float inv = 1.0f / (lA * aA + lB * aB);
            aA *= inv; aB *= inv;
#pragma unroll
            for (int g = 0; g < 4; ++g) {
                float v = o[g][j] * aA + oX[(wq * 16 + q) * 68 + g * 16 + ln] * aB;
                long idx = ((long)b * L_ + q0 + q) * D_ + h * DH_ + g * 16 + ln;
                Og[idx] = f2bf(v);
            }
        }
    }
}

// ---------------- launch ----------------
extern "C" void kernel_launch(void* const* d_in, const int* in_sizes, int n_in,
                              void* d_out, int out_size, void* d_ws, size_t ws_size,
                              hipStream_t stream)
{
    const float* qx = (const float*)d_in[0];
    const float* kx = (const float*)d_in[1];
    const float* vx = (const float*)d_in[2];
    const float* ec = (const float*)d_in[3];
    const float* Wq = (const float*)d_in[4];
    const float* bq = (const float*)d_in[5];
    const float* Wk = (const float*)d_in[6];
    const float* bk = (const float*)d_in[7];
    const float* Wv = (const float*)d_in[8];
    const float* bv = (const float*)d_in[9];
    const float* Wo = (const float*)d_in[10];
    const float* bo = (const float*)d_in[11];
    float* out = (float*)d_out;

    const long NA = (long)B_ * L_ * D_;
    const long NW = (long)D_ * D_;

    unsigned short* qb  = (unsigned short*)d_ws;
    unsigned short* kb  = qb + NA;
    unsigned short* vb  = kb + NA;
    unsigned short* wqb = vb + NA;
    unsigned short* wkb = wqb + NW;
    unsigned short* wvb = wkb + NW;
    unsigned short* wob = wvb + NW;
    unsigned short* Qp  = wob + NW;
    unsigned short* Kp  = Qp + NA;
    unsigned short* Vtp = Kp + NA;       // V^T: [D][B*L], slot-swizzled
    unsigned short* Ap  = qb;            // alias: qb dead after Q GEMM
    float*          mk  = (float*)(Vtp + NA);

    const long total4 = (3 * NA + 4 * NW) / 4;
    const long nblk = (total4 + B_ * L_ + 255) / 256;
    cvt_mask_kernel<<<dim3((unsigned)nblk), dim3(256), 0, stream>>>(
        qx, kx, vx, Wq, Wk, Wv, Wo, ec, qb, kb, vb, wqb, wkb, wvb, wob, mk);

    // fused QKV projections (1536 blocks, 5 blocks/CU): Q scaled, K plain,
    // V transposed+swizzled
    GemmArgs zq = {qb, wqb, bq, Qp, 1};
    GemmArgs zk = {kb, wkb, bk, Kp, 0};
    GemmArgs zv = {vb, wvb, bv, Vtp, 2};
    gemm_kernel<64, 64><<<dim3(8, 64, 3), dim3(256), 0, stream>>>(zq, zk, zv, B_ * L_, D_, D_);

    attn_kernel<<<dim3(L_ / 64, B_ * H_), dim3(512), 0, stream>>>(Qp, Kp, Vtp, mk, Ap);

    // output projection, f32 out (1024 blocks, 4 blocks/CU)
    GemmArgs zo = {Ap, wob, bo, out, 3};
    gemm_kernel<32, 64><<<dim3(8, 128, 1), dim3(256), 0, stream>>>(zo, zo, zo, B_ * L_, D_, D_);
}